// Round 1
// baseline (153.366 us; speedup 1.0000x reference)
//
#include <hip/hip_runtime.h>
#include <math.h>

#define B_N 4096
#define M_N 256
#define D_N 256
#define ROWS 4

constexpr float TAU_   = 0.2f;
constexpr float LAM_   = 8.0f;
constexpr float TOPO_  = 0.5f;
constexpr float LEN_C_ = 0.01f;
constexpr float SP_C_  = 0.001f;
constexpr float LOG2E_ = 1.44269504088896340736f;

// ws layout (floats):
// [0]=S_data  [1]=S_p  [2]=S_wpd
// [16..272)   degree[256]
// [512..768)  wnorm[256]
// [1024..5120) dnorm[4096]
// [8192..73728) wT[256*256]  (D x M)   -- total ~288 KB

__device__ __forceinline__ float wave_reduce_sum(float v) {
#pragma unroll
    for (int off = 32; off > 0; off >>= 1) v += __shfl_down(v, off, 64);
    return v;
}

// block j: transpose weights row -> wT column, compute wnorm[j]
__global__ void k_wprep(const float* __restrict__ w, float* __restrict__ wT,
                        float* __restrict__ wnorm) {
    __shared__ float red[4];
    int j = blockIdx.x, d = threadIdx.x;
    float v = w[j * D_N + d];
    wT[d * M_N + j] = v;
    float s = wave_reduce_sum(v * v);
    int lane = d & 63, wid = d >> 6;
    if (lane == 0) red[wid] = s;
    __syncthreads();
    if (d == 0) wnorm[j] = red[0] + red[1] + red[2] + red[3];
}

// block b: dnorm[b] = sum_d data[b,d]^2
__global__ void k_dnorm(const float* __restrict__ data, float* __restrict__ dnorm) {
    __shared__ float red[4];
    int b = blockIdx.x, d = threadIdx.x;
    float v = data[b * D_N + d];
    float s = wave_reduce_sum(v * v);
    int lane = d & 63, wid = d >> 6;
    if (lane == 0) red[wid] = s;
    __syncthreads();
    if (d == 0) dnorm[b] = red[0] + red[1] + red[2] + red[3];
}

// block j: edge_prob row stats + weighted proto-dist sums
__global__ void k_edge(const float* __restrict__ w, const float* __restrict__ E,
                       float* __restrict__ degree, float* __restrict__ S_p,
                       float* __restrict__ S_wpd) {
    __shared__ float swj[D_N];
    __shared__ float redp[4], redw[4];
    int j = blockIdx.x, k = threadIdx.x;
    swj[k] = w[j * D_N + k];
    __syncthreads();

    float l = 0.5f * (E[j * M_N + k] + E[k * M_N + j]);
    float p = __builtin_amdgcn_rcpf(1.0f + __builtin_amdgcn_exp2f(-l * LOG2E_));
    if (k == j) p = 0.0f;

    // proto_dist[j,k] = ||w_j - w_k||^2 (direct, no cancellation)
    float pd = 0.0f;
    const float4* wr = (const float4*)(w + (size_t)k * D_N);
    const float4* sw = (const float4*)swj;
#pragma unroll 4
    for (int i = 0; i < D_N / 4; i++) {
        float4 a = wr[i], b = sw[i];
        float dx = a.x - b.x, dy = a.y - b.y, dz = a.z - b.z, dw = a.w - b.w;
        pd += dx * dx + dy * dy + dz * dz + dw * dw;
    }

    float sp  = wave_reduce_sum(p);
    float spd = wave_reduce_sum(p * pd);
    int lane = k & 63, wid = k >> 6;
    if (lane == 0) { redp[wid] = sp; redw[wid] = spd; }
    __syncthreads();
    if (k == 0) {
        float tp  = redp[0] + redp[1] + redp[2] + redp[3];
        float tpd = redw[0] + redw[1] + redw[2] + redw[3];
        degree[j] = tp * (1.0f / (float)(M_N - 1));
        atomicAdd(S_p, tp);
        atomicAdd(S_wpd, tpd);
    }
}

// main: distances + soft-rank + neighborhood, 4 data rows per block
__global__ __launch_bounds__(256) void k_main(
    const float* __restrict__ data, const float* __restrict__ wT,
    const float* __restrict__ dnorm, const float* __restrict__ wnorm,
    const float* __restrict__ degree, float* __restrict__ S_data) {
    __shared__ float sdata[ROWS][D_N];
    __shared__ float sdist[ROWS][M_N];
    __shared__ float sscal[ROWS][M_N];
    __shared__ float red[4];

    int j  = threadIdx.x;
    int b0 = blockIdx.x * ROWS;

#pragma unroll
    for (int r = 0; r < ROWS; r++) sdata[r][j] = data[(size_t)(b0 + r) * D_N + j];
    __syncthreads();

    // Phase 1: dot(data[b0+r], w[j]) via coalesced wT loads
    float acc[ROWS] = {0.f, 0.f, 0.f, 0.f};
#pragma unroll 4
    for (int d = 0; d < D_N; d++) {
        float wv = wT[d * M_N + j];
#pragma unroll
        for (int r = 0; r < ROWS; r++) acc[r] += wv * sdata[r][d];
    }

    float wn = wnorm[j];
    float fj = 1.0f + TOPO_ * degree[j];
#pragma unroll
    for (int r = 0; r < ROWS; r++) {
        float sq = dnorm[b0 + r] - 2.0f * acc[r] + wn;
        float dist = sqrtf(fmaxf(sq, 0.0f));
        sdist[r][j] = dist;
        sscal[r][j] = dist * (LOG2E_ / TAU_);
    }
    __syncthreads();

    // Phase 3: soft rank. sum_k sigmoid((d_j-d_k)/tau) over ALL k, then -0.5
    // (diagonal term is exactly 0.5). sigma(x) = 1/(1+exp2((d_k-d_j)*log2e/tau))
    float tsum = 0.0f;
#pragma unroll
    for (int r = 0; r < ROWS; r++) {
        float mj = -sscal[r][j];
        float s = 0.0f;
#pragma unroll 8
        for (int k = 0; k < M_N; k++) {
            float t = __builtin_amdgcn_exp2f(sscal[r][k] + mj);
            s += __builtin_amdgcn_rcpf(1.0f + t);
        }
        // neighborhood = exp(-(soft_rank-1)/LAM), soft_rank-1 = s-0.5
        float nb = __builtin_amdgcn_exp2f(-(s - 0.5f) * (LOG2E_ / LAM_));
        tsum += nb * sdist[r][j] * fj;
    }

    float bs = wave_reduce_sum(tsum);
    int lane = j & 63, wid = j >> 6;
    if (lane == 0) red[wid] = bs;
    __syncthreads();
    if (j == 0) atomicAdd(S_data, red[0] + red[1] + red[2] + red[3]);
}

__global__ void k_final(const float* __restrict__ acc, float* __restrict__ out) {
    float S_data = acc[0], S_p = acc[1], S_wpd = acc[2];
    float data_term = S_data * (1.0f / (float)(B_N * M_N));
    float wl = S_wpd / (S_p + 1e-8f);
    float sp = S_p * (1.0f / (float)(M_N * M_N));
    out[0] = data_term + LEN_C_ * wl + SP_C_ * sp;
}

extern "C" void kernel_launch(void* const* d_in, const int* in_sizes, int n_in,
                              void* d_out, int out_size, void* d_ws, size_t ws_size,
                              hipStream_t stream) {
    const float* data = (const float*)d_in[0];
    const float* w    = (const float*)d_in[1];
    const float* E    = (const float*)d_in[2];
    float* ws     = (float*)d_ws;
    float* Sacc   = ws;            // 3 accumulators
    float* degree = ws + 16;
    float* wnorm  = ws + 512;
    float* dnorm  = ws + 1024;
    float* wT     = ws + 8192;

    hipMemsetAsync(Sacc, 0, 16 * sizeof(float), stream);
    k_wprep<<<M_N, D_N, 0, stream>>>(w, wT, wnorm);
    k_dnorm<<<B_N, D_N, 0, stream>>>(data, dnorm);
    k_edge <<<M_N, M_N, 0, stream>>>(w, E, degree, Sacc + 1, Sacc + 2);
    k_main <<<B_N / ROWS, M_N, 0, stream>>>(data, wT, dnorm, wnorm, degree, Sacc);
    k_final<<<1, 1, 0, stream>>>(Sacc, (float*)d_out);
}

// Round 2
// 134.713 us; speedup vs baseline: 1.1385x; 1.1385x over previous
//
#include <hip/hip_runtime.h>
#include <math.h>

#define B_N 4096
#define M_N 256
#define D_N 256
#define ROWS 4
#define GRID_MAIN (B_N / ROWS)

constexpr float TAU_   = 0.2f;
constexpr float LAM_   = 8.0f;
constexpr float TOPO_  = 0.5f;
constexpr float LEN_C_ = 0.01f;
constexpr float SP_C_  = 0.001f;
constexpr float LOG2E_ = 1.44269504088896340736f;
constexpr float KSC    = LOG2E_ / TAU_;   // dist -> log2-sigmoid scale
constexpr float KL     = LOG2E_ / LAM_;

// ws float layout:
// [0]        S_data accumulator
// [4]        block-completion counter (uint)
// [16..272)  degree[256]
// [512..768) wnorm[256]
// [1024..1280) pPart[256]   (per-edge-block sum of edge_prob)
// [1280..1536) wpdPart[256] (per-edge-block sum of p*proto_dist)
// [8192..73728) wT[256*256] (D x M transpose)   total ~288 KB

__device__ __forceinline__ float wave_reduce_sum(float v) {
#pragma unroll
    for (int off = 32; off > 0; off >>= 1) v += __shfl_down(v, off, 64);
    return v;
}

// Dispatch 1: blocks 0..255 transpose w + wnorm (+ block 0 zeroes accumulators);
//             blocks 256..511 edge-probability stats (self-contained).
__global__ __launch_bounds__(256) void k_prep(const float* __restrict__ w,
                                              const float* __restrict__ E,
                                              float* __restrict__ ws) {
    float* wT = ws + 8192;
    int tid = threadIdx.x;
    if (blockIdx.x < M_N) {
        int j = blockIdx.x;
        __shared__ float red[4];
        float v = w[j * D_N + tid];
        wT[tid * M_N + j] = v;
        float s = wave_reduce_sum(v * v);
        if ((tid & 63) == 0) red[tid >> 6] = s;
        if (j == 0 && tid < 16) ws[tid] = 0.0f;  // S_data + counter
        __syncthreads();
        if (tid == 0) ws[512 + j] = red[0] + red[1] + red[2] + red[3];
    } else {
        int j = blockIdx.x - M_N;
        __shared__ float swj[D_N];
        __shared__ float redp[4], redw[4];
        int k = tid;
        swj[k] = w[j * D_N + k];
        __syncthreads();

        float l = 0.5f * (E[j * M_N + k] + E[k * M_N + j]);
        float p = __builtin_amdgcn_rcpf(1.0f + __builtin_amdgcn_exp2f(-l * LOG2E_));
        if (k == j) p = 0.0f;

        float pd = 0.0f;
        const float4* wr = (const float4*)(w + (size_t)k * D_N);
        const float4* sw = (const float4*)swj;
#pragma unroll 8
        for (int i = 0; i < D_N / 4; i++) {
            float4 a = wr[i], b = sw[i];
            float dx = a.x - b.x, dy = a.y - b.y, dz = a.z - b.z, dw = a.w - b.w;
            pd += dx * dx + dy * dy + dz * dz + dw * dw;
        }

        float sp  = wave_reduce_sum(p);
        float spd = wave_reduce_sum(p * pd);
        if ((k & 63) == 0) { redp[k >> 6] = sp; redw[k >> 6] = spd; }
        __syncthreads();
        if (k == 0) {
            float tp = redp[0] + redp[1] + redp[2] + redp[3];
            float tw = redw[0] + redw[1] + redw[2] + redw[3];
            ws[16 + j]   = tp * (1.0f / (float)(M_N - 1));
            ws[1024 + j] = tp;
            ws[1280 + j] = tw;
        }
    }
}

// Dispatch 2: distances + soft-rank + data term; last block finalizes loss.
__global__ __launch_bounds__(256, 4) void k_main(const float* __restrict__ data,
                                                 float* __restrict__ ws,
                                                 float* __restrict__ out) {
    const float* wT     = ws + 8192;
    const float* degree = ws + 16;
    const float* wnorm  = ws + 512;
    float* S_data = ws;
    unsigned* cnt = (unsigned*)(ws + 4);

    __shared__ float  sdata[ROWS][D_N];
    __shared__ float  sdist[ROWS][M_N];
    __shared__ float4 e4[M_N];
    __shared__ float  redn[4][ROWS];
    __shared__ float  snorm[ROWS];
    __shared__ float  redf[4];
    __shared__ int    isLast;

    int j = threadIdx.x;
    int b0 = blockIdx.x * ROWS;
    int lane = j & 63, wid = j >> 6;

    // stage data rows + row norms (fused dnorm)
    float v[ROWS];
#pragma unroll
    for (int r = 0; r < ROWS; r++) {
        v[r] = data[(size_t)(b0 + r) * D_N + j];
        sdata[r][j] = v[r];
    }
#pragma unroll
    for (int r = 0; r < ROWS; r++) {
        float s = wave_reduce_sum(v[r] * v[r]);
        if (lane == 0) redn[wid][r] = s;
    }
    __syncthreads();
    if (j < ROWS) snorm[j] = redn[0][j] + redn[1][j] + redn[2][j] + redn[3][j];
    __syncthreads();

    // dot(data_r, w_j) via coalesced wT loads
    float a0 = 0.f, a1 = 0.f, a2 = 0.f, a3 = 0.f;
#pragma unroll 8
    for (int d = 0; d < D_N; d++) {
        float wv = wT[d * M_N + j];
        a0 = fmaf(wv, sdata[0][d], a0);
        a1 = fmaf(wv, sdata[1][d], a1);
        a2 = fmaf(wv, sdata[2][d], a2);
        a3 = fmaf(wv, sdata[3][d], a3);
    }
    float wn = wnorm[j];
    float acc[ROWS] = {a0, a1, a2, a3};
    float dr[ROWS];
#pragma unroll
    for (int r = 0; r < ROWS; r++) {
        float sq = snorm[r] - 2.0f * acc[r] + wn;
        dr[r] = sqrtf(fmaxf(sq, 0.0f));
        sdist[r][j] = dr[r];
    }
    __syncthreads();

    // e_k = 2^(sc_k - c_r) precompute; iv_j = 1/e_j
    float iv[ROWS], iv2[ROWS], ee[ROWS];
#pragma unroll
    for (int r = 0; r < ROWS; r++) {
        float c = sdist[r][0] * KSC;
        ee[r]  = __builtin_amdgcn_exp2f(fmaf(dr[r], KSC, -c));
        iv[r]  = __builtin_amdgcn_rcpf(ee[r]);
        iv2[r] = iv[r] * iv[r];
    }
    e4[j] = make_float4(ee[0], ee[1], ee[2], ee[3]);
    __syncthreads();

    // soft-rank: sum_k sigmoid((d_j-d_k)/tau), pair-combined (1 rcp per 2 k's)
    // 1/(1+a)+1/(1+b) = (t+2)/((t+1)+ab), t=a+b=iv*(ea+eb), ab=iv2*(ea*eb)
    float s0 = 0.f, s1 = 0.f, s2 = 0.f, s3 = 0.f;
#pragma unroll 4
    for (int k = 0; k < M_N; k += 2) {
        float4 ea = e4[k], eb = e4[k + 1];
        {
            float es = ea.x + eb.x, ep = ea.x * eb.x;
            float t = iv[0] * es, u = t + 1.0f;
            float den = fmaf(iv2[0], ep, u);
            s0 = fmaf(u + 1.0f, __builtin_amdgcn_rcpf(den), s0);
        }
        {
            float es = ea.y + eb.y, ep = ea.y * eb.y;
            float t = iv[1] * es, u = t + 1.0f;
            float den = fmaf(iv2[1], ep, u);
            s1 = fmaf(u + 1.0f, __builtin_amdgcn_rcpf(den), s1);
        }
        {
            float es = ea.z + eb.z, ep = ea.z * eb.z;
            float t = iv[2] * es, u = t + 1.0f;
            float den = fmaf(iv2[2], ep, u);
            s2 = fmaf(u + 1.0f, __builtin_amdgcn_rcpf(den), s2);
        }
        {
            float es = ea.w + eb.w, ep = ea.w * eb.w;
            float t = iv[3] * es, u = t + 1.0f;
            float den = fmaf(iv2[3], ep, u);
            s3 = fmaf(u + 1.0f, __builtin_amdgcn_rcpf(den), s3);
        }
    }

    // neighborhood * dist * (1 + TOPO*degree_j); diagonal contributes exactly 0.5
    float fj = 1.0f + TOPO_ * degree[j];
    float ss[ROWS] = {s0, s1, s2, s3};
    float tl = 0.0f;
#pragma unroll
    for (int r = 0; r < ROWS; r++) {
        float nb = __builtin_amdgcn_exp2f((0.5f - ss[r]) * KL);
        tl = fmaf(nb, dr[r], tl);
    }
    tl *= fj;

    float bs = wave_reduce_sum(tl);
    if (lane == 0) redf[wid] = bs;
    __syncthreads();
    if (j == 0) {
        float tot = redf[0] + redf[1] + redf[2] + redf[3];
        atomicAdd(S_data, tot);
        __threadfence();
        unsigned t = atomicAdd(cnt, 1u);
        isLast = (t == (unsigned)(GRID_MAIN - 1)) ? 1 : 0;
    }
    __syncthreads();

    if (isLast) {
        float p  = ws[1024 + j];
        float wd = ws[1280 + j];
        float rp = wave_reduce_sum(p);
        float rw = wave_reduce_sum(wd);
        if (lane == 0) { redn[wid][0] = rp; redn[wid][1] = rw; }
        __syncthreads();
        if (j == 0) {
            float Sp   = redn[0][0] + redn[1][0] + redn[2][0] + redn[3][0];
            float Swpd = redn[0][1] + redn[1][1] + redn[2][1] + redn[3][1];
            float Sd   = atomicAdd(S_data, 0.0f);  // coherent read
            float data_term = Sd * (1.0f / ((float)B_N * (float)M_N));
            float wl = Swpd / (Sp + 1e-8f);
            float sparsity = Sp * (1.0f / ((float)M_N * (float)M_N));
            out[0] = data_term + LEN_C_ * wl + SP_C_ * sparsity;
        }
    }
}

extern "C" void kernel_launch(void* const* d_in, const int* in_sizes, int n_in,
                              void* d_out, int out_size, void* d_ws, size_t ws_size,
                              hipStream_t stream) {
    const float* data = (const float*)d_in[0];
    const float* w    = (const float*)d_in[1];
    const float* E    = (const float*)d_in[2];
    float* ws = (float*)d_ws;

    k_prep<<<2 * M_N, 256, 0, stream>>>(w, E, ws);
    k_main<<<GRID_MAIN, 256, 0, stream>>>(data, ws, (float*)d_out);
}